// Round 1
// baseline (72.983 us; speedup 1.0000x reference)
//
#include <hip/hip_runtime.h>

#define T_DIM 1024
#define B_DIM 4
#define D_DIM 512
#define NROWS (T_DIM * B_DIM)
// out layout: [4 scales][T*B rows][4 o][D]
#define SISTRIDE ((size_t)NROWS * 4 * D_DIM)

// ---------------- Kernel 1: per-(b,t) inverse L2 norm over D ----------------
__global__ __launch_bounds__(256) void norm_kernel(const float* __restrict__ x,
                                                   float* __restrict__ inv) {
    const int wave = threadIdx.x >> 6;
    const int lane = threadIdx.x & 63;
    const int row  = blockIdx.x * 4 + wave;          // grid = NROWS/4 exactly
    const float4* xr = reinterpret_cast<const float4*>(x + (size_t)row * D_DIM);
    float4 a = xr[lane];
    float4 c = xr[lane + 64];
    float s2 = a.x*a.x + a.y*a.y + a.z*a.z + a.w*a.w
             + c.x*c.x + c.y*c.y + c.z*c.z + c.w*c.w;
    #pragma unroll
    for (int off = 32; off > 0; off >>= 1) s2 += __shfl_xor(s2, off, 64);
    if (lane == 0) inv[row] = 1.0f / fmaxf(sqrtf(s2), 1e-12f);
}

// ---------------- Kernel 2: weighted window combine ----------------
template<int SI, int S>
__device__ __forceinline__ void do_scale_interior(const float* __restrict__ W,
                                                  const float xv[32],
                                                  float* __restrict__ outrow) {
    constexpr int base = 16 - S / 2;   // window start offset within xv (compile-time)
    #pragma unroll
    for (int o = 0; o < 4; ++o) {
        float acc = 0.f;
        #pragma unroll
        for (int k = 0; k < S; ++k)
            acc += W[o * S + k] * xv[base + k];
        outrow[(size_t)SI * SISTRIDE + (size_t)o * D_DIM] = acc;
    }
}

template<int SI, int S>
__device__ __forceinline__ void do_scale_generic(const float* __restrict__ W,
                                                 const float* __restrict__ x,
                                                 const float* __restrict__ inv,
                                                 int j, int b, int d,
                                                 float* __restrict__ outrow) {
    const int lo = max(0, j - S / 2 + 1);
    const int hi = min(j + S / 2, T_DIM - 1);
    const size_t xbase = (size_t)b * T_DIM * D_DIM + d;
    #pragma unroll
    for (int o = 0; o < 4; ++o) {
        float acc = 0.f;
        #pragma unroll
        for (int k = 0; k < S; ++k) {
            const int t = lo + k;
            if (t <= hi)
                acc += W[o * S + k] * x[xbase + (size_t)t * D_DIM] * inv[b * T_DIM + t];
        }
        outrow[(size_t)SI * SISTRIDE + (size_t)o * D_DIM] = acc;
    }
}

__global__ __launch_bounds__(512) void pool_kernel(const float* __restrict__ x,
                                                   const float* __restrict__ inv,
                                                   const float* __restrict__ W0,
                                                   const float* __restrict__ W1,
                                                   const float* __restrict__ W2,
                                                   const float* __restrict__ W3,
                                                   float* __restrict__ out) {
    const int d = threadIdx.x;           // 512 threads, one per feature dim
    const int j = blockIdx.x % T_DIM;    // adjacent blocks -> adjacent j (L2 reuse)
    const int b = blockIdx.x / T_DIM;
    const int n = j * B_DIM + b;         // reference row order: (T, B) flattened
    float* outrow = out + (size_t)n * 4 * D_DIM + d;

    if (j >= 15 && j <= T_DIM - 17) {
        // Interior: all four windows live inside [j-15, j+16], no masking needed.
        __shared__ float sinv[32];
        const int t0 = j - 15;
        if (threadIdx.x < 32) sinv[threadIdx.x] = inv[b * T_DIM + t0 + threadIdx.x];
        __syncthreads();
        float xv[32];
        const size_t xoff = (size_t)b * T_DIM * D_DIM + (size_t)t0 * D_DIM + d;
        #pragma unroll
        for (int i = 0; i < 32; ++i)
            xv[i] = x[xoff + (size_t)i * D_DIM] * sinv[i];
        do_scale_interior<0, 4 >(W0, xv, outrow);
        do_scale_interior<1, 8 >(W1, xv, outrow);
        do_scale_interior<2, 16>(W2, xv, outrow);
        do_scale_interior<3, 32>(W3, xv, outrow);
    } else {
        // Boundary (124 of 4096 blocks): generic masked path, reload from cache.
        do_scale_generic<0, 4 >(W0, x, inv, j, b, d, outrow);
        do_scale_generic<1, 8 >(W1, x, inv, j, b, d, outrow);
        do_scale_generic<2, 16>(W2, x, inv, j, b, d, outrow);
        do_scale_generic<3, 32>(W3, x, inv, j, b, d, outrow);
    }
}

extern "C" void kernel_launch(void* const* d_in, const int* in_sizes, int n_in,
                              void* d_out, int out_size, void* d_ws, size_t ws_size,
                              hipStream_t stream) {
    const float* x  = (const float*)d_in[0];
    const float* W0 = (const float*)d_in[1];
    const float* W1 = (const float*)d_in[2];
    const float* W2 = (const float*)d_in[3];
    const float* W3 = (const float*)d_in[4];
    float* out = (float*)d_out;
    float* inv = (float*)d_ws;   // NROWS floats = 16 KB scratch

    norm_kernel<<<NROWS / 4, 256, 0, stream>>>(x, inv);
    pool_kernel<<<NROWS, 512, 0, stream>>>(x, inv, W0, W1, W2, W3, out);
}

// Round 3
// 46.901 us; speedup vs baseline: 1.5561x; 1.5561x over previous
//
#include <hip/hip_runtime.h>

#define T_DIM 1024
#define B_DIM 4
#define D_DIM 512
#define DQ (D_DIM / 4)                 // 128 float4 per row
#define NROWS (T_DIM * B_DIM)
#define SSTR ((size_t)NROWS * 4 * DQ)  // scale-slab stride in float4 units

// ---------------- Kernel 1: per-(b,t) inverse L2 norm over D ----------------
__global__ __launch_bounds__(256) void norm_kernel(const float* __restrict__ x,
                                                   float* __restrict__ inv) {
    const int wave = threadIdx.x >> 6;
    const int lane = threadIdx.x & 63;
    const int row  = blockIdx.x * 4 + wave;          // grid = NROWS/4 exactly
    const float4* xr = reinterpret_cast<const float4*>(x) + (size_t)row * DQ;
    float4 a = xr[lane];
    float4 c = xr[lane + 64];
    float s2 = a.x*a.x + a.y*a.y + a.z*a.z + a.w*a.w
             + c.x*c.x + c.y*c.y + c.z*c.z + c.w*c.w;
    #pragma unroll
    for (int off = 32; off > 0; off >>= 1) s2 += __shfl_xor(s2, off, 64);
    if (lane == 0) inv[row] = 1.0f / fmaxf(sqrtf(s2), 1e-12f);
}

// ---------------- Kernel 2: weighted window combine (float4 per thread) -----
__device__ __forceinline__ void fma4(float4& a, float wt, const float4& v) {
    a.x += wt * v.x; a.y += wt * v.y; a.z += wt * v.z; a.w += wt * v.w;
}

template<int S>
__device__ __forceinline__ void gen_scale(const float* __restrict__ W,
                                          const float4* __restrict__ xq,
                                          const float* __restrict__ inv,
                                          int j, int b,
                                          float4& a0, float4& a1,
                                          float4& a2, float4& a3) {
    const int lo = max(0, j - S / 2 + 1);
    const int hi = min(j + S / 2, T_DIM - 1);
    for (int t = lo; t <= hi; ++t) {
        float4 xv = xq[(size_t)t * DQ];
        const float s = inv[b * T_DIM + t];
        xv.x *= s; xv.y *= s; xv.z *= s; xv.w *= s;
        const int kk = t - lo;
        fma4(a0, W[0 * S + kk], xv);
        fma4(a1, W[1 * S + kk], xv);
        fma4(a2, W[2 * S + kk], xv);
        fma4(a3, W[3 * S + kk], xv);
    }
}

__global__ __launch_bounds__(128) void pool_kernel(const float* __restrict__ x,
                                                   const float* __restrict__ inv,
                                                   const float* __restrict__ W0,
                                                   const float* __restrict__ W1,
                                                   const float* __restrict__ W2,
                                                   const float* __restrict__ W3,
                                                   float* __restrict__ out) {
    // Bijective XCD-contiguous remap: XCD k gets blocks [k*512, (k+1)*512).
    const int bid = (blockIdx.x & 7) * (NROWS / 8) + (blockIdx.x >> 3);
    const int j = bid & (T_DIM - 1);
    const int b = bid >> 10;                 // T_DIM == 1024
    const int n = j * B_DIM + b;             // reference row order: (T, B)
    const int dq = threadIdx.x;              // one float4 of D per thread
    const float4* xq  = reinterpret_cast<const float4*>(x) + (size_t)b * T_DIM * DQ + dq;
    float4* outq      = reinterpret_cast<float4*>(out) + (size_t)n * 4 * DQ + dq;

    float4 acc[16];                          // [si*4 + o], all indices compile-time
    #pragma unroll
    for (int i = 0; i < 16; ++i) acc[i] = make_float4(0.f, 0.f, 0.f, 0.f);

    if (j >= 15 && j <= T_DIM - 17) {
        // Interior: all four windows live inside [j-15, j+16].
        __shared__ float sinv[32];
        const int t0 = j - 15;
        if (threadIdx.x < 32) sinv[threadIdx.x] = inv[b * T_DIM + t0 + threadIdx.x];
        __syncthreads();
        #pragma unroll
        for (int k = 0; k < 32; ++k) {       // k compile-time after unroll
            float4 xv = xq[(size_t)(t0 + k) * DQ];
            const float s = sinv[k];
            xv.x *= s; xv.y *= s; xv.z *= s; xv.w *= s;
            if (k >= 14 && k < 18) {         // scale 4, base 14
                #pragma unroll
                for (int o = 0; o < 4; ++o) fma4(acc[0 + o], W0[o * 4 + (k - 14)], xv);
            }
            if (k >= 12 && k < 20) {         // scale 8, base 12
                #pragma unroll
                for (int o = 0; o < 4; ++o) fma4(acc[4 + o], W1[o * 8 + (k - 12)], xv);
            }
            if (k >= 8 && k < 24) {          // scale 16, base 8
                #pragma unroll
                for (int o = 0; o < 4; ++o) fma4(acc[8 + o], W2[o * 16 + (k - 8)], xv);
            }
            {                                // scale 32, base 0
                #pragma unroll
                for (int o = 0; o < 4; ++o) fma4(acc[12 + o], W3[o * 32 + k], xv);
            }
        }
    } else {
        // Boundary (124 of 4096 blocks): masked streaming path.
        gen_scale<4 >(W0, xq, inv, j, b, acc[0],  acc[1],  acc[2],  acc[3]);
        gen_scale<8 >(W1, xq, inv, j, b, acc[4],  acc[5],  acc[6],  acc[7]);
        gen_scale<16>(W2, xq, inv, j, b, acc[8],  acc[9],  acc[10], acc[11]);
        gen_scale<32>(W3, xq, inv, j, b, acc[12], acc[13], acc[14], acc[15]);
    }

    #pragma unroll
    for (int si = 0; si < 4; ++si)
        #pragma unroll
        for (int o = 0; o < 4; ++o)
            outq[(size_t)si * SSTR + (size_t)o * DQ] = acc[si * 4 + o];
}

extern "C" void kernel_launch(void* const* d_in, const int* in_sizes, int n_in,
                              void* d_out, int out_size, void* d_ws, size_t ws_size,
                              hipStream_t stream) {
    const float* x  = (const float*)d_in[0];
    const float* W0 = (const float*)d_in[1];
    const float* W1 = (const float*)d_in[2];
    const float* W2 = (const float*)d_in[3];
    const float* W3 = (const float*)d_in[4];
    float* out = (float*)d_out;
    float* inv = (float*)d_ws;   // NROWS floats = 16 KB scratch

    norm_kernel<<<NROWS / 4, 256, 0, stream>>>(x, inv);
    pool_kernel<<<NROWS, 128, 0, stream>>>(x, inv, W0, W1, W2, W3, out);
}

// Round 5
// 45.634 us; speedup vs baseline: 1.5993x; 1.0278x over previous
//
#include <hip/hip_runtime.h>

#define T_DIM 1024
#define B_DIM 4
#define D_DIM 512
#define DQ (D_DIM / 4)                 // 128 float4 per row
#define NROWS (T_DIM * B_DIM)
#define SSTR ((size_t)NROWS * 4 * DQ)  // scale-slab stride in float4 units
#define JT 8                           // j-rows per block
#define NTILES (NROWS / JT)            // 512 blocks
#define ROWS_ST (JT + 31)              // 39 staged rows per tile

typedef float f32x4 __attribute__((ext_vector_type(4)));

__device__ __forceinline__ void nt_store4(const float4& v, float4* p) {
    __builtin_nontemporal_store(*reinterpret_cast<const f32x4*>(&v),
                                reinterpret_cast<f32x4*>(p));
}

// ---------------- Kernel 1: per-(b,t) inverse L2 norm over D ----------------
__global__ __launch_bounds__(256) void norm_kernel(const float* __restrict__ x,
                                                   float* __restrict__ inv) {
    const int wave = threadIdx.x >> 6;
    const int lane = threadIdx.x & 63;
    const int row  = blockIdx.x * 4 + wave;          // grid = NROWS/4 exactly
    const float4* xr = reinterpret_cast<const float4*>(x) + (size_t)row * DQ;
    float4 a = xr[lane];
    float4 c = xr[lane + 64];
    float s2 = a.x*a.x + a.y*a.y + a.z*a.z + a.w*a.w
             + c.x*c.x + c.y*c.y + c.z*c.z + c.w*c.w;
    #pragma unroll
    for (int off = 32; off > 0; off >>= 1) s2 += __shfl_xor(s2, off, 64);
    if (lane == 0) inv[row] = 1.0f / fmaxf(sqrtf(s2), 1e-12f);
}

// ---------------- Kernel 2: j-tiled weighted window combine ----------------
__device__ __forceinline__ void fma4(float4& a, float wt, const float4& v) {
    a.x += wt * v.x; a.y += wt * v.y; a.z += wt * v.z; a.w += wt * v.w;
}

template<int S>
__device__ __forceinline__ void gen_scale(const float* __restrict__ W,
                                          const float4* __restrict__ xq,
                                          const float* __restrict__ inv,
                                          int j, int b,
                                          float4* acc) {   // acc[0..3]
    const int lo = max(0, j - S / 2 + 1);
    const int hi = min(j + S / 2, T_DIM - 1);
    for (int t = lo; t <= hi; ++t) {
        float4 xv = xq[(size_t)t * DQ];
        const float s = inv[b * T_DIM + t];
        xv.x *= s; xv.y *= s; xv.z *= s; xv.w *= s;
        const int kk = t - lo;
        fma4(acc[0], W[0 * S + kk], xv);
        fma4(acc[1], W[1 * S + kk], xv);
        fma4(acc[2], W[2 * S + kk], xv);
        fma4(acc[3], W[3 * S + kk], xv);
    }
}

__global__ __launch_bounds__(256) void pool_kernel(const float* __restrict__ x,
                                                   const float* __restrict__ inv,
                                                   const float* __restrict__ W0,
                                                   const float* __restrict__ W1,
                                                   const float* __restrict__ W2,
                                                   const float* __restrict__ W3,
                                                   float* __restrict__ out) {
    __shared__ float4 xs[ROWS_ST * DQ];              // 39 * 128 * 16 B = 78 KB
    // Bijective XCD-contiguous remap: XCD k gets 64 consecutive tiles.
    const int tile = (blockIdx.x & 7) * (NTILES / 8) + (blockIdx.x >> 3);
    const int b  = tile >> 7;                        // 128 tiles per b
    const int j0 = (tile & 127) * JT;
    const int q  = threadIdx.x & 127;                // d-quad
    const int jg = threadIdx.x >> 7;                 // j-group 0/1
    const float4* xqb = reinterpret_cast<const float4*>(x) + (size_t)b * T_DIM * DQ;

    if (j0 >= 16) {
        // ---- Fast path: stage 39 normalized rows once (zero-fill t >= T). ----
        for (int l = jg; l < ROWS_ST; l += 2) {
            const int t = j0 - 15 + l;
            float4 v = make_float4(0.f, 0.f, 0.f, 0.f);
            if (t < T_DIM) {
                v = xqb[(size_t)t * DQ + q];
                const float s = inv[b * T_DIM + t];
                v.x *= s; v.y *= s; v.z *= s; v.w *= s;
            }
            xs[l * DQ + q] = v;
        }
        __syncthreads();

        for (int jj = 0; jj < 4; ++jj) {             // NOT unrolled: keep I-cache small
            const int u = jg * 4 + jj;               // j offset within tile (0..7)
            const int j = j0 + u;
            const float4* xrow = &xs[u * DQ + q];    // window rows u .. u+31
            float4 acc[16];
            #pragma unroll
            for (int i = 0; i < 16; ++i) acc[i] = make_float4(0.f, 0.f, 0.f, 0.f);
            #pragma unroll
            for (int k = 0; k < 32; ++k) {           // compile-time LDS offsets
                const float4 xv = xrow[k * DQ];
                if (k >= 14 && k < 18) {             // scale 4, base 14
                    #pragma unroll
                    for (int o = 0; o < 4; ++o) fma4(acc[0 + o], W0[o * 4 + (k - 14)], xv);
                }
                if (k >= 12 && k < 20) {             // scale 8, base 12
                    #pragma unroll
                    for (int o = 0; o < 4; ++o) fma4(acc[4 + o], W1[o * 8 + (k - 12)], xv);
                }
                if (k >= 8 && k < 24) {              // scale 16, base 8
                    #pragma unroll
                    for (int o = 0; o < 4; ++o) fma4(acc[8 + o], W2[o * 16 + (k - 8)], xv);
                }
                {                                    // scale 32, base 0
                    #pragma unroll
                    for (int o = 0; o < 4; ++o) fma4(acc[12 + o], W3[o * 32 + k], xv);
                }
            }
            const int n = j * B_DIM + b;             // reference row order (T, B)
            float4* outq = reinterpret_cast<float4*>(out) + (size_t)n * 4 * DQ + q;
            #pragma unroll
            for (int si = 0; si < 4; ++si)
                #pragma unroll
                for (int o = 0; o < 4; ++o)
                    nt_store4(acc[si * 4 + o], &outq[(size_t)si * SSTR + (size_t)o * DQ]);
        }
    } else {
        // ---- Left-edge tiles (j0 in {0,8}; 8 of 512 blocks): shifted windows. ----
        const float4* xq = xqb + q;
        for (int jj = 0; jj < 4; ++jj) {
            const int j = j0 + jg * 4 + jj;
            float4 acc[16];
            #pragma unroll
            for (int i = 0; i < 16; ++i) acc[i] = make_float4(0.f, 0.f, 0.f, 0.f);
            gen_scale<4 >(W0, xq, inv, j, b, &acc[0]);
            gen_scale<8 >(W1, xq, inv, j, b, &acc[4]);
            gen_scale<16>(W2, xq, inv, j, b, &acc[8]);
            gen_scale<32>(W3, xq, inv, j, b, &acc[12]);
            const int n = j * B_DIM + b;
            float4* outq = reinterpret_cast<float4*>(out) + (size_t)n * 4 * DQ + q;
            #pragma unroll
            for (int si = 0; si < 4; ++si)
                #pragma unroll
                for (int o = 0; o < 4; ++o)
                    nt_store4(acc[si * 4 + o], &outq[(size_t)si * SSTR + (size_t)o * DQ]);
        }
    }
}

extern "C" void kernel_launch(void* const* d_in, const int* in_sizes, int n_in,
                              void* d_out, int out_size, void* d_ws, size_t ws_size,
                              hipStream_t stream) {
    const float* x  = (const float*)d_in[0];
    const float* W0 = (const float*)d_in[1];
    const float* W1 = (const float*)d_in[2];
    const float* W2 = (const float*)d_in[3];
    const float* W3 = (const float*)d_in[4];
    float* out = (float*)d_out;
    float* inv = (float*)d_ws;   // NROWS floats = 16 KB scratch

    norm_kernel<<<NROWS / 4, 256, 0, stream>>>(x, inv);
    pool_kernel<<<NTILES, 256, 0, stream>>>(x, inv, W0, W1, W2, W3, out);
}